// Round 7
// baseline (298.032 us; speedup 1.0000x reference)
//
#include <hip/hip_runtime.h>
#include <math.h>

// ---------- types ----------
typedef __attribute__((ext_vector_type(8)))  short  short8;   // 8 bf16 (4 VGPRs) MFMA A/B frag
typedef __attribute__((ext_vector_type(16))) float  f32x16;   // 32x32 MFMA C/D frag
typedef __attribute__((ext_vector_type(4)))  float  float4v;
typedef __attribute__((ext_vector_type(8)))  unsigned short ushort8;
typedef __attribute__((ext_vector_type(4)))  unsigned short ushort4v;

#define NDIM 4096
#define BM 256
#define BN 256
#define BK 64
#define T_TILES (NDIM / BK)   // 64
#define IMG_USH 8192          // one half-tile image: 1024 chunks x 16B = 16 KB

// fp32 -> bf16, round-to-nearest-even
__device__ __forceinline__ unsigned short f2bf(float f) {
  unsigned u = __builtin_bit_cast(unsigned, f);
  u += 0x7fffu + ((u >> 16) & 1u);
  return (unsigned short)(u >> 16);
}

// async global->LDS DMA, 16B/lane. LDS dest must be wave-uniform base + lane*16.
__device__ __forceinline__ void gload_lds16(const unsigned short* g, unsigned short* l) {
  __builtin_amdgcn_global_load_lds(
      (const __attribute__((address_space(1))) void*)g,
      (__attribute__((address_space(3))) void*)l, 16, 0, 0);
}

// ---------- prep: emit A and W^T as FRAGMENT-MAJOR images (unchanged, verified R6) ----------
// Image (per 128-row half x 64-k tile) = 1024 16B-chunks; chunk index
// s = (p*4+h)*64 + fh*32 + fr  <->  rows p*32+fr, k-bytes h*32+fh*16.
// GEMM stages with src = base + tid*16 (linear DMA) and reads frags at
// base + lane*16 (contiguous per wave -> zero bank conflicts).
__global__ __launch_bounds__(256)
void prep(const float* __restrict__ A, unsigned short* __restrict__ Abf,
          const float* __restrict__ W, unsigned short* __restrict__ Wt) {
  const int t = threadIdx.x;
  if (blockIdx.x < 2048) {
    const int b  = blockIdx.x;
    const int mb = b >> 6, kt = b & 63;
    const int h  = (t >> 6) & 3, fh = (t >> 5) & 1, fr = t & 31;
    const float* src0 = A + (size_t)(mb * 128 + fr) * NDIM + kt * 64 + h * 16 + fh * 8;
    unsigned short* dst = Abf + ((size_t)(mb * 64 + kt) * 1024 + t) * 8;
#pragma unroll
    for (int p = 0; p < 4; ++p) {            // chunk p*256 + t
      const float* s = src0 + (size_t)(p * 32) * NDIM;
      float4v a = *(const float4v*)s;
      float4v c = *(const float4v*)(s + 4);
      ushort8 o;
      o[0] = f2bf(a[0]); o[1] = f2bf(a[1]); o[2] = f2bf(a[2]); o[3] = f2bf(a[3]);
      o[4] = f2bf(c[0]); o[5] = f2bf(c[1]); o[6] = f2bf(c[2]); o[7] = f2bf(c[3]);
      *(ushort8*)(dst + (size_t)p * 2048) = o;
    }
  } else {
    const int b  = blockIdx.x - 2048;
    const int nb = b >> 6, kt = b & 63;
    const int n0 = (t & 31) * 4;             // local n quad base (0..124)
    const int kq = t >> 5;                   // k octet 0..7
    float4v v[8];
#pragma unroll
    for (int r = 0; r < 8; ++r)              // 512B contiguous per (kq,r) row
      v[r] = *(const float4v*)&W[(size_t)(kt * 64 + kq * 8 + r) * NDIM + nb * 128 + n0];
    const int q  = (t & 31) >> 3;            // n-subtile 0..3
    const int h  = kq >> 1, fh = kq & 1;
    unsigned short* img = Wt + (size_t)(nb * 64 + kt) * IMG_USH;
#pragma unroll
    for (int c = 0; c < 4; ++c) {            // register transpose -> full chunks
      const int fr = (n0 + c) & 31;
      ushort8 o;
#pragma unroll
      for (int r = 0; r < 8; ++r) o[r] = f2bf(v[r][c]);
      *(ushort8*)(img + ((size_t)((q * 4 + h) * 64 + fh * 32 + fr)) * 8) = o;
    }
  }
}

// ---------- gemm: 256x256, 8 waves, FREE-RUN tile schedule (2 barriers/tile) ----------
// R7: R6 falsified bank-conflicts (0, no speedup) -> limiter = phase schedule.
// R6's 8 barriers/tile locked all waves into [read]/[MFMA] alternation and put
// lgkmcnt(0) between reads and their MFMAs (full LDS latency exposed, ~750cy
// overhead/phase vs 512cy MFMA). Restructure: per tile only a mid-tile barrier
// and an end-of-tile (gate+barrier). Within a tile, waves free-run; each
// phase's af-frags are ds_read ONE PHASE EARLY, so the compiler's counted
// lgkm waits retire reads issued ~512cy earlier (latency hidden), and reads
// of one wave overlap MFMAs of its SIMD-sibling.
// Ring safety:
//  - A parity-2-ring: tile u reads parity u&1; stageA(u+1) writes parity
//    (u+1)&1 -> never the read parity. Cross-tile skew bounded by end barrier.
//  - B parity-2-ring: stageB(u+2) writes parity u&1 = the slot bk was read
//    from at tile start. Mid-tile barrier (between af1-MFMA and stageB issues)
//    guarantees every wave's bk ds_reads are lgkm-retired (they retire before
//    that wave's p0 MFMA) before any wave issues the overwrite DMA.
//  - end-of-tile gate vmcnt(4): steady queue (oldest first) = [B(u+1):4,
//    A(u+1):4, B(u+2):4] -> drain 8, leave B(u+2) in flight. u==T-2: vmcnt(0)
//    (queue [B(T-1):4, A(T-1):4], all needed). u==T-1: no gate/barrier.
//    Barrier after gate publishes all waves' DMA completions.
// Fragment-major images: every ds_read/DMA is base+lane*16, conflict-free.
// C/D mapping unchanged: col=lane&31, row=(reg&3)+8*(reg>>2)+4*(lane>>5).
__global__ __launch_bounds__(512, 2)
void gemm_bt_quant(const unsigned short* __restrict__ Abf,
                   const unsigned short* __restrict__ Wt,
                   const float* __restrict__ bias,
                   float* __restrict__ C) {
  __shared__ unsigned short lds[8 * IMG_USH];   // A[par][half] x4, B[par][half] x4

  const int tid  = threadIdx.x;            // 0..511
  const int lane = tid & 63;
  const int wid  = tid >> 6;               // 8 waves: 2M x 4N
  const int wr   = wid >> 2;               // 0..1  (A half)
  const int wc   = wid & 3;                // 0..3
  const int hb   = wc >> 1;                // B half this wave reads

  // XCD-bijective swizzle (256 blocks % 8 == 0)
  const int bid  = blockIdx.y * 16 + blockIdx.x;
  const int swz  = (bid & 7) * 32 + (bid >> 3);
  const int m0   = (swz >> 4) * BM;
  const int n0   = (swz & 15) * BN;
  const int mb0  = (swz >> 4) * 2;
  const int nb0  = (swz & 15) * 2;

  const unsigned short* Aimg = Abf + (size_t)mb0 * 64 * IMG_USH;
  const unsigned short* Bimg = Wt  + (size_t)nb0 * 64 * IMG_USH;

  auto stageA = [&](int t2, int ha) {      // -> A slot [t2&1][ha]
    unsigned short* dst = &lds[((t2 & 1) * 2 + ha) * IMG_USH];
    const unsigned short* src = Aimg + ((size_t)(ha * 64 + t2)) * IMG_USH + tid * 8;
    gload_lds16(src,        dst + tid * 8);
    gload_lds16(src + 4096, dst + 4096 + tid * 8);
  };
  auto stageB = [&](int t2, int h2) {      // -> B slot [t2&1][h2]
    unsigned short* dst = &lds[(4 + (t2 & 1) * 2 + h2) * IMG_USH];
    const unsigned short* src = Bimg + ((size_t)(h2 * 64 + t2)) * IMG_USH + tid * 8;
    gload_lds16(src,        dst + tid * 8);
    gload_lds16(src + 4096, dst + 4096 + tid * 8);
  };

  f32x16 acc[4][2] = {};

  // prologue: B(0), A(0), B(1); gate leaves B(1) in flight
  stageB(0, 0); stageB(0, 1);
  stageA(0, 0); stageA(0, 1);
  stageB(1, 0); stageB(1, 1);
  asm volatile("s_waitcnt vmcnt(4)" ::: "memory");
  __builtin_amdgcn_s_barrier();
  __builtin_amdgcn_sched_barrier(0);

  const int lofs = lane * 8;               // per-lane chunk offset (ushorts)

  for (int u = 0; u < T_TILES; ++u) {
    const unsigned short* Ah = &lds[((u & 1) * 2 + wr) * IMG_USH];
    const unsigned short* Bh = &lds[(4 + (u & 1) * 2 + hb) * IMG_USH + (wc & 1) * 4096];
    short8 bk[2][4], af0[4], af1[4], af2[4], af3[4];

    // ---- p0: bk + af0 reads, stage A(u+1,0), prefetch af1, MFMA m0
#pragma unroll
    for (int j = 0; j < 2; ++j)
#pragma unroll
      for (int h = 0; h < 4; ++h)
        bk[j][h] = *(const short8*)&Bh[j * 2048 + h * 512 + lofs];
#pragma unroll
    for (int h = 0; h < 4; ++h)
      af0[h] = *(const short8*)&Ah[0 * 2048 + h * 512 + lofs];
    if (u + 1 < T_TILES) stageA(u + 1, 0);
#pragma unroll
    for (int h = 0; h < 4; ++h)
      af1[h] = *(const short8*)&Ah[1 * 2048 + h * 512 + lofs];
    __builtin_amdgcn_s_setprio(1);
#pragma unroll
    for (int h = 0; h < 4; ++h)
#pragma unroll
      for (int j = 0; j < 2; ++j)
        acc[0][j] = __builtin_amdgcn_mfma_f32_32x32x16_bf16(af0[h], bk[j][h], acc[0][j], 0, 0, 0);
    __builtin_amdgcn_s_setprio(0);
    __builtin_amdgcn_sched_barrier(0);

    // ---- p1: stage A(u+1,1), prefetch af2, MFMA m1
    if (u + 1 < T_TILES) stageA(u + 1, 1);
#pragma unroll
    for (int h = 0; h < 4; ++h)
      af2[h] = *(const short8*)&Ah[2 * 2048 + h * 512 + lofs];
    __builtin_amdgcn_s_setprio(1);
#pragma unroll
    for (int h = 0; h < 4; ++h)
#pragma unroll
      for (int j = 0; j < 2; ++j)
        acc[1][j] = __builtin_amdgcn_mfma_f32_32x32x16_bf16(af1[h], bk[j][h], acc[1][j], 0, 0, 0);
    __builtin_amdgcn_s_setprio(0);
    __builtin_amdgcn_sched_barrier(0);

    // ---- mid barrier: all waves' bk reads retired before B-slot overwrite
    __builtin_amdgcn_s_barrier();
    __builtin_amdgcn_sched_barrier(0);

    // ---- p2: stage B(u+2,0), prefetch af3, MFMA m2
    if (u + 2 < T_TILES) stageB(u + 2, 0);
#pragma unroll
    for (int h = 0; h < 4; ++h)
      af3[h] = *(const short8*)&Ah[3 * 2048 + h * 512 + lofs];
    __builtin_amdgcn_s_setprio(1);
#pragma unroll
    for (int h = 0; h < 4; ++h)
#pragma unroll
      for (int j = 0; j < 2; ++j)
        acc[2][j] = __builtin_amdgcn_mfma_f32_32x32x16_bf16(af2[h], bk[j][h], acc[2][j], 0, 0, 0);
    __builtin_amdgcn_s_setprio(0);
    __builtin_amdgcn_sched_barrier(0);

    // ---- p3: stage B(u+2,1), MFMA m3
    if (u + 2 < T_TILES) stageB(u + 2, 1);
    __builtin_amdgcn_s_setprio(1);
#pragma unroll
    for (int h = 0; h < 4; ++h)
#pragma unroll
      for (int j = 0; j < 2; ++j)
        acc[3][j] = __builtin_amdgcn_mfma_f32_32x32x16_bf16(af3[h], bk[j][h], acc[3][j], 0, 0, 0);
    __builtin_amdgcn_s_setprio(0);

    // ---- end of tile: gate own DMAs, publish via barrier
    if (u < T_TILES - 1) {
      if (u < T_TILES - 2) asm volatile("s_waitcnt vmcnt(4)" ::: "memory");
      else                 asm volatile("s_waitcnt vmcnt(0)" ::: "memory");
      __builtin_amdgcn_s_barrier();
      __builtin_amdgcn_sched_barrier(0);
    }
  }

  // epilogue: fused quant + bias
  const int fr = lane & 31;
  const int fh = lane >> 5;
  const float inv = 1.0f / 256.0f;
#pragma unroll
  for (int j = 0; j < 2; ++j) {
    const int col = n0 + wc * 64 + j * 32 + fr;
    const float qb = rintf(bias[col] * 256.0f) * inv;
#pragma unroll
    for (int p = 0; p < 4; ++p) {
      const int rb = m0 + wr * 128 + p * 32 + 4 * fh;
#pragma unroll
      for (int r = 0; r < 16; ++r) {
        const int row = rb + (r & 3) + 8 * (r >> 2);
        C[(size_t)row * NDIM + col] = rintf(acc[p][j][r] * 256.0f) * inv + qb;
      }
    }
  }
}

// ---------- fallback (ws too small): fp32 tiled GEMM, exact ----------
__global__ void gemm_fb(const float* __restrict__ A, const float* __restrict__ W,
                        const float* __restrict__ bias, float* __restrict__ C) {
  __shared__ float As[32][33], Ws[32][33];
  int tx = threadIdx.x, ty = threadIdx.y;     // (32,8)
  int m0 = blockIdx.y * 32, n0 = blockIdx.x * 32;
  float acc[4] = {0.f, 0.f, 0.f, 0.f};
  for (int k0 = 0; k0 < NDIM; k0 += 32) {
#pragma unroll
    for (int i = 0; i < 4; ++i) {
      int r = ty + i * 8;
      As[r][tx] = A[(size_t)(m0 + r) * NDIM + k0 + tx];
      Ws[r][tx] = W[(size_t)(k0 + r) * NDIM + n0 + tx];
    }
    __syncthreads();
#pragma unroll
    for (int k = 0; k < 32; ++k) {
      float wv = Ws[k][tx];
#pragma unroll
      for (int i = 0; i < 4; ++i) acc[i] += As[ty + i * 8][k] * wv;
    }
    __syncthreads();
  }
  float qb = rintf(bias[n0 + tx] * 256.0f) * (1.0f / 256.0f);
#pragma unroll
  for (int i = 0; i < 4; ++i)
    C[(size_t)(m0 + ty + i * 8) * NDIM + n0 + tx] =
        rintf(acc[i] * 256.0f) * (1.0f / 256.0f) + qb;
}

extern "C" void kernel_launch(void* const* d_in, const int* in_sizes, int n_in,
                              void* d_out, int out_size, void* d_ws, size_t ws_size,
                              hipStream_t stream) {
  const float* A    = (const float*)d_in[0];
  const float* W    = (const float*)d_in[1];
  const float* bias = (const float*)d_in[2];
  float* C = (float*)d_out;
  const size_t nElem = (size_t)NDIM * NDIM;

  if (ws_size >= nElem * 4) {   // need 2 bf16 matrices = 64 MB
    unsigned short* Abf = (unsigned short*)d_ws;
    unsigned short* Wt  = Abf + nElem;
    prep<<<4096, 256, 0, stream>>>(A, Abf, W, Wt);
    gemm_bt_quant<<<dim3(16, 16), 512, 0, stream>>>(Abf, Wt, bias, C);
  } else {
    gemm_fb<<<dim3(128, 128), dim3(32, 8), 0, stream>>>(A, W, bias, C);
  }
}